// Round 1
// baseline (388.171 us; speedup 1.0000x reference)
//
#include <hip/hip_runtime.h>
#include <hip/hip_bf16.h>

// ---------------------------------------------------------------------------
// SemanticActor fused forward, bf16 MFMA (gfx950) — Round 9
// R8 post-mortem: actor_main 116us, MfmaUtil 31%, Occupancy 20% -> exactly
// 1 block/CU (LDS 82944B: 2x doesn't fit in 160KB). With one resident block,
// all ~13 barriers are full-CU drains; MFMA floor is ~41us, LDS floor ~47us,
// so the missing 2x is overlap, not pipe saturation.
// R9: single-buffer HsBuf (65KB->32KB, +1 barrier/pair, +2 in tail). LDS
// 50176B -> 2 blocks/CU. __launch_bounds__(512,4) pins VGPR<=128 (currently
// exactly 128) so 4 waves/SIMD materialize. Cross-block TLP now hides barrier
// drains + W1P prefetch + GEMM1<->GEMM2 LDS latency.
// ---------------------------------------------------------------------------

#define B_TOTAL 65536
#define TROWS   64
#define RSTR    136   // rawS row stride elems: 272B = 17x16B -> optimal b128 phasing

typedef __attribute__((ext_vector_type(8))) short s8v;   // 8 x bf16
typedef __attribute__((ext_vector_type(4))) float f4v;   // MFMA C/D

__constant__ int c_PI[6] = {0,0,1,1,2,2};
__constant__ int c_PJ[6] = {1,2,0,2,0,1};
__constant__ int c_PF[6] = {0,0,1,0,1,1};
// inverse of FIRST_INDS / SECOND_INDS: raw ag/g col -> X col (or -1)
__constant__ int c_INV[2][30] = {
  {0,1,2,3,4,5,6,7,8,9,10,11,12,13,-1,14,15,16,-1,-1,17,18,-1,-1,-1,19,-1,-1,-1,-1},
  {0,1,2,3,4,5,6,7,8,9,-1,-1,-1,-1,10,-1,-1,-1,11,12,-1,-1,13,14,15,-1,16,17,18,19}};

static __device__ __forceinline__ short bf16s(float v) {
  __hip_bfloat16 h = __float2bfloat16(v);
  union { __hip_bfloat16 h; short s; } u; u.h = h; return u.s;
}

// ---- prep: one 512-elem fragment per wave; coalesced reads, b128 writes ----
// tasks: [0,384) W1P (p=wid>>6, nb=rem>>2, ks=rem&3) | [384,512) W2f |
//        [512,640) W3f | [640,648) W4f
__global__ __launch_bounds__(256)
void prep_weights(const float* __restrict__ phi_w1,
                  const float* __restrict__ phi_b1,
                  const float* __restrict__ phi_w2,
                  const float* __restrict__ rho_w1,
                  const float* __restrict__ mean_w,
                  const float* __restrict__ logstd_w,
                  __hip_bfloat16* __restrict__ W1P,
                  __hip_bfloat16* __restrict__ W2f,
                  __hip_bfloat16* __restrict__ W3f,
                  __hip_bfloat16* __restrict__ W4f) {
  const int wid  = (blockIdx.x * blockDim.x + threadIdx.x) >> 6;
  const int lane = threadIdx.x & 63;
  const int l15  = lane & 15;
  const int kq   = (lane >> 4) * 8;
  if (wid >= 648) return;
  union { short s[8]; s8v v; } o;
  __hip_bfloat16* dst;
  if (wid < 384) {
    const int p = wid >> 6, rem = wid & 63;
    const int nb = rem >> 2, ks = rem & 3;
    const int n = nb * 16 + l15;
    const int f = c_PF[p], oi = c_PI[p], oj = c_PJ[p];
#pragma unroll
    for (int j = 0; j < 8; ++j) {
      int k = ks * 32 + kq + j;
      float v = 0.0f;
      if (k < 30)       { int t = c_INV[f][k];      if (t >= 0) v = phi_w1[t * 256 + n]; }
      else if (k < 60)  { int t = c_INV[f][k - 30]; if (t >= 0) v = phi_w1[(30 + t) * 256 + n]; }
      else if (k < 70)  { v = phi_w1[(20 + k - 60) * 256 + n]; }
      else if (k < 115) { int q = (k - 70) / 15, t = (k - 70) - q * 15;
                          int c = (q == oi) ? 50 + t : (q == oj) ? 65 + t : -1;
                          if (c >= 0) v = phi_w1[c * 256 + n]; }
      else if (k == 115) v = phi_b1[n];   // bias via ones-column
      o.s[j] = bf16s(v);
    }
    dst = W1P + wid * 512 + lane * 8;
  } else if (wid < 512) {
    const int r = wid - 384;
    const int nb = r >> 3, ks = r & 7;
    const int n = nb * 16 + l15;
#pragma unroll
    for (int j = 0; j < 8; ++j)
      o.s[j] = bf16s(phi_w2[(ks * 32 + kq + j) * 256 + n]);
    dst = W2f + r * 512 + lane * 8;
  } else if (wid < 640) {
    const int r = wid - 512;
    const int nb = r >> 3, ks = r & 7;
    const int n = nb * 16 + l15;
#pragma unroll
    for (int j = 0; j < 8; ++j)
      o.s[j] = bf16s(rho_w1[(ks * 32 + kq + j) * 256 + n]);
    dst = W3f + r * 512 + lane * 8;
  } else {
    const int ks = wid - 640;
    const int n = l15;
#pragma unroll
    for (int j = 0; j < 8; ++j) {
      int k = ks * 32 + kq + j;
      float v = (n < 4) ? mean_w[k * 4 + n]
              : (n < 8) ? logstd_w[k * 4 + (n - 4)] : 0.0f;
      o.s[j] = bf16s(v);
    }
    dst = W4f + ks * 512 + lane * 8;
  }
  *reinterpret_cast<s8v*>(dst) = o.v;
}

static __device__ __forceinline__ unsigned pk2(float a, float b) {
  __hip_bfloat162 h = __float22bfloat162_rn(float2{a, b});
  union { __hip_bfloat162 h2; unsigned u; } cv; cv.h2 = h;
  return cv.u;
}

// ---- main: 512 threads (8 waves), 64 rows/block, wave = 32-col slice -------
// LDS 50176B -> 2 blocks/CU; launch_bounds(512,4) pins VGPR<=128 (4 waves/EU)
__global__ __launch_bounds__(512, 4)
void actor_main(const float* __restrict__ obs, const float* __restrict__ ag,
                const float* __restrict__ g,
                const __hip_bfloat16* __restrict__ W1P,
                const __hip_bfloat16* __restrict__ W2f,
                const __hip_bfloat16* __restrict__ W3f,
                const __hip_bfloat16* __restrict__ W4f,
                const float* __restrict__ b2, const float* __restrict__ b3,
                const float* __restrict__ meanb,
                const float* __restrict__ logstdb,
                float* __restrict__ out) {
  __shared__ __align__(16) __hip_bfloat16 rawS[TROWS * RSTR];   // 17408 B
  __shared__ __align__(16) __hip_bfloat16 HsBuf[4 * 8 * 512];   // 32768 B

  const int tid  = threadIdx.x;
  const int lane = tid & 63;
  const int w    = tid >> 6;      // wave 0..7 -> hidden cols [32w, 32w+32)
  const int l15  = lane & 15;
  const int quad = lane >> 4;
  const int r0   = blockIdx.x * TROWS;

  float4 b2v[2];
#pragma unroll
  for (int i = 0; i < 2; ++i)
    b2v[i] = *(const float4*)&b2[w * 32 + i * 16 + quad * 4];

  // persistent W2 fragments (once per block)
  s8v w2f[8][2];
#pragma unroll
  for (int i = 0; i < 2; ++i)
#pragma unroll
    for (int ks = 0; ks < 8; ++ks)
      w2f[ks][i] = *(const s8v*)&W2f[(((w * 2 + i) * 8 + ks) * 512) + lane * 8];

  // stage raw input [ag|g|obs|1|0] bf16 K=128 (vectorized: 2 b128 stores/thread)
  {
    const int row = tid >> 3;           // 0..63
    const int c0  = (tid & 7) * 16;     // 0..112
    const float* agr = ag  + (size_t)(r0 + row) * 30;
    const float* gr  = g   + (size_t)(r0 + row) * 30;
    const float* obr = obs + (size_t)(r0 + row) * 55;
    union { short s[16]; s8v v[2]; } o;
#pragma unroll
    for (int cc = 0; cc < 16; ++cc) {
      int c = c0 + cc;
      float v;
      if      (c < 30)  v = agr[c];
      else if (c < 60)  v = gr[c - 30];
      else if (c < 115) v = obr[c - 60];
      else if (c == 115) v = 1.0f;
      else              v = 0.0f;
      o.s[cc] = bf16s(v);
    }
    *reinterpret_cast<s8v*>(&rawS[row * RSTR + c0])     = o.v[0];
    *reinterpret_cast<s8v*>(&rawS[row * RSTR + c0 + 8]) = o.v[1];
  }

  // preload pair 0's W1P frags
  s8v w1c[4][2], w1n[4][2];
#pragma unroll
  for (int i = 0; i < 2; ++i)
#pragma unroll
    for (int ks = 0; ks < 4; ++ks)
      w1c[ks][i] = *(const s8v*)&W1P[(((w * 2 + i) * 4 + ks) * 512) + lane * 8];

  f4v agg[2][4];
#pragma unroll
  for (int i = 0; i < 2; ++i)
#pragma unroll
    for (int rt = 0; rt < 4; ++rt) agg[i][rt] = f4v{0.f, 0.f, 0.f, 0.f};

  const int ebase = l15 * 8 + (quad >> 1) * 128 + (quad & 1) * 4;

  __syncthreads();  // rawS staged

#pragma unroll 1
  for (int p = 0; p < 6; ++p) {
    __hip_bfloat16* buf = &HsBuf[0];

    // prefetch NEXT pair's W1P frags early (consumed only after GEMM2:
    // latency hidden under GEMM1 MFMAs + barriers + GEMM2 and, with 2
    // resident blocks, under the other block's compute)
    if (p < 5) {
      const __hip_bfloat16* nb = W1P + (p + 1) * 32768;
#pragma unroll
      for (int i = 0; i < 2; ++i)
#pragma unroll
        for (int ks = 0; ks < 4; ++ks)
          w1n[ks][i] = *(const s8v*)&nb[(((w * 2 + i) * 4 + ks) * 512) + lane * 8];
    }

    // GEMM1: h = W1P[p](A) x raw(B); K=128; raw B-frags from LDS
    f4v h[2][4];
#pragma unroll
    for (int i = 0; i < 2; ++i)
#pragma unroll
      for (int rt = 0; rt < 4; ++rt) h[i][rt] = f4v{0.f, 0.f, 0.f, 0.f};
#pragma unroll
    for (int ks = 0; ks < 4; ++ks) {
      s8v bx[4];
#pragma unroll
      for (int rt = 0; rt < 4; ++rt)
        bx[rt] = *(const s8v*)&rawS[(rt * 16 + l15) * RSTR + ks * 32 + quad * 8];
#pragma unroll
      for (int i = 0; i < 2; ++i)
#pragma unroll
        for (int rt = 0; rt < 4; ++rt)
          h[i][rt] = __builtin_amdgcn_mfma_f32_16x16x32_bf16(w1c[ks][i], bx[rt], h[i][rt], 0, 0, 0);
    }

    __syncthreads();  // pair p-1's GEMM2 reads of buf complete (single buffer)

    // epilogue: relu (bias folded via ones-column), pack -> b64 writes
#pragma unroll
    for (int i = 0; i < 2; ++i)
#pragma unroll
      for (int rt = 0; rt < 4; ++rt) {
        float v0 = fmaxf(h[i][rt][0], 0.f);
        float v1 = fmaxf(h[i][rt][1], 0.f);
        float v2 = fmaxf(h[i][rt][2], 0.f);
        float v3 = fmaxf(h[i][rt][3], 0.f);
        uint2 U; U.x = pk2(v0, v1); U.y = pk2(v2, v3);
        *reinterpret_cast<uint2*>(&buf[(rt * 8 + w) * 512 + i * 256 + ebase]) = U;
      }
    __syncthreads();  // H(p) visible

    // GEMM2: a2 = W2(A) x H(B); K=256; agg += relu(a2 + b2)
    f4v a2[2][4];
#pragma unroll
    for (int i = 0; i < 2; ++i)
#pragma unroll
      for (int rt = 0; rt < 4; ++rt) a2[i][rt] = f4v{0.f, 0.f, 0.f, 0.f};
#pragma unroll
    for (int ks = 0; ks < 8; ++ks) {
      s8v hf[4];
#pragma unroll
      for (int rt = 0; rt < 4; ++rt)
        hf[rt] = *(const s8v*)&buf[(rt * 8 + ks) * 512 + lane * 8];
#pragma unroll
      for (int i = 0; i < 2; ++i)
#pragma unroll
        for (int rt = 0; rt < 4; ++rt)
          a2[i][rt] = __builtin_amdgcn_mfma_f32_16x16x32_bf16(w2f[ks][i], hf[rt], a2[i][rt], 0, 0, 0);
    }
#pragma unroll
    for (int i = 0; i < 2; ++i)
#pragma unroll
      for (int rt = 0; rt < 4; ++rt) {
        agg[i][rt][0] += fmaxf(a2[i][rt][0] + b2v[i].x, 0.f);
        agg[i][rt][1] += fmaxf(a2[i][rt][1] + b2v[i].y, 0.f);
        agg[i][rt][2] += fmaxf(a2[i][rt][2] + b2v[i].z, 0.f);
        agg[i][rt][3] += fmaxf(a2[i][rt][3] + b2v[i].w, 0.f);
      }

    // rotate prefetch buffer
    if (p < 5) {
#pragma unroll
      for (int i = 0; i < 2; ++i)
#pragma unroll
        for (int ks = 0; ks < 4; ++ks)
          w1c[ks][i] = w1n[ks][i];
    }
  }

  // W3 frags + b3 (late-loaded)
  s8v w3f[8][2];
#pragma unroll
  for (int i = 0; i < 2; ++i)
#pragma unroll
    for (int ks = 0; ks < 8; ++ks)
      w3f[ks][i] = *(const s8v*)&W3f[(((w * 2 + i) * 8 + ks) * 512) + lane * 8];
  float4 b3v[2];
#pragma unroll
  for (int i = 0; i < 2; ++i)
    b3v[i] = *(const float4*)&b3[w * 32 + i * 16 + quad * 4];

  __syncthreads();  // last pair's GEMM2 reads done before stash overwrites buf

  // stash agg (bf16) into buf, frag-major
  {
    __hip_bfloat16* bufA = &HsBuf[0];
#pragma unroll
    for (int i = 0; i < 2; ++i)
#pragma unroll
      for (int rt = 0; rt < 4; ++rt) {
        uint2 U; U.x = pk2(agg[i][rt][0], agg[i][rt][1]);
        U.y = pk2(agg[i][rt][2], agg[i][rt][3]);
        *reinterpret_cast<uint2*>(&bufA[(rt * 8 + w) * 512 + i * 256 + ebase]) = U;
      }
  }
  __syncthreads();

  // GEMM3: hr = relu(W3(A) x agg(B) + b3); reads buf, then rewrites buf
  f4v a3[2][4];
#pragma unroll
  for (int i = 0; i < 2; ++i)
#pragma unroll
    for (int rt = 0; rt < 4; ++rt) a3[i][rt] = f4v{0.f, 0.f, 0.f, 0.f};
  {
    const __hip_bfloat16* bufA = &HsBuf[0];
#pragma unroll
    for (int ks = 0; ks < 8; ++ks) {
      s8v hf[4];
#pragma unroll
      for (int rt = 0; rt < 4; ++rt)
        hf[rt] = *(const s8v*)&bufA[(rt * 8 + ks) * 512 + lane * 8];
#pragma unroll
      for (int i = 0; i < 2; ++i)
#pragma unroll
        for (int rt = 0; rt < 4; ++rt)
          a3[i][rt] = __builtin_amdgcn_mfma_f32_16x16x32_bf16(w3f[ks][i], hf[rt], a3[i][rt], 0, 0, 0);
    }
  }
  __syncthreads();  // all GEMM3 reads of buf complete before rewrite
  {
    __hip_bfloat16* bufB = &HsBuf[0];
#pragma unroll
    for (int i = 0; i < 2; ++i)
#pragma unroll
      for (int rt = 0; rt < 4; ++rt) {
        float v0 = fmaxf(a3[i][rt][0] + b3v[i].x, 0.f);
        float v1 = fmaxf(a3[i][rt][1] + b3v[i].y, 0.f);
        float v2 = fmaxf(a3[i][rt][2] + b3v[i].z, 0.f);
        float v3 = fmaxf(a3[i][rt][3] + b3v[i].w, 0.f);
        uint2 U; U.x = pk2(v0, v1); U.y = pk2(v2, v3);
        *reinterpret_cast<uint2*>(&bufB[(rt * 8 + w) * 512 + i * 256 + ebase]) = U;
      }
  }
  __syncthreads();

  // GEMM4: heads; waves 0..3 take batch tile rt=w; reads buf
  if (w < 4) {
    const __hip_bfloat16* bufB = &HsBuf[0];
    f4v a4 = f4v{0.f, 0.f, 0.f, 0.f};
#pragma unroll
    for (int ks = 0; ks < 8; ++ks) {
      s8v w4 = *(const s8v*)&W4f[ks * 512 + lane * 8];
      s8v hf = *(const s8v*)&bufB[(w * 8 + ks) * 512 + lane * 8];
      a4 = __builtin_amdgcn_mfma_f32_16x16x32_bf16(w4, hf, a4, 0, 0, 0);
    }
    const int row = r0 + w * 16 + l15;
    if (quad == 0) {          // head cols 0..3 = mean
      float4 mb = *(const float4*)meanb;
      float4 o;
      o.x = a4[0] + mb.x; o.y = a4[1] + mb.y;
      o.z = a4[2] + mb.z; o.w = a4[3] + mb.w;
      *reinterpret_cast<float4*>(&out[(size_t)row * 4]) = o;
    } else if (quad == 1) {   // head cols 4..7 = logstd (clipped)
      float4 lb = *(const float4*)logstdb;
      float4 o;
      o.x = fminf(fmaxf(a4[0] + lb.x, -20.f), 2.f);
      o.y = fminf(fmaxf(a4[1] + lb.y, -20.f), 2.f);
      o.z = fminf(fmaxf(a4[2] + lb.z, -20.f), 2.f);
      o.w = fminf(fmaxf(a4[3] + lb.w, -20.f), 2.f);
      *reinterpret_cast<float4*>(&out[(size_t)B_TOTAL * 4 + (size_t)row * 4]) = o;
    }
  }
}

extern "C" void kernel_launch(void* const* d_in, const int* in_sizes, int n_in,
                              void* d_out, int out_size, void* d_ws, size_t ws_size,
                              hipStream_t stream) {
  const float* obs      = (const float*)d_in[0];
  const float* ag       = (const float*)d_in[1];
  const float* g        = (const float*)d_in[2];
  const float* phi_w1   = (const float*)d_in[3];
  const float* phi_b1   = (const float*)d_in[4];
  const float* phi_w2   = (const float*)d_in[5];
  const float* phi_b2   = (const float*)d_in[6];
  const float* rho_w1   = (const float*)d_in[7];
  const float* rho_b1   = (const float*)d_in[8];
  const float* mean_w   = (const float*)d_in[9];
  const float* mean_b   = (const float*)d_in[10];
  const float* logstd_w = (const float*)d_in[11];
  const float* logstd_b = (const float*)d_in[12];
  float* out = (float*)d_out;

  // ws (bf16): W1P 6x32768 | W2f 65536 | W3f 65536 | W4f 4096 elems
  char* ws = (char*)d_ws;
  __hip_bfloat16* W1P = (__hip_bfloat16*)(ws);
  __hip_bfloat16* W2f = (__hip_bfloat16*)(ws + 393216);
  __hip_bfloat16* W3f = (__hip_bfloat16*)(ws + 393216 + 131072);
  __hip_bfloat16* W4f = (__hip_bfloat16*)(ws + 393216 + 262144);

  prep_weights<<<162, 256, 0, stream>>>(phi_w1, phi_b1, phi_w2, rho_w1,
                                        mean_w, logstd_w, W1P, W2f, W3f, W4f);
  actor_main<<<B_TOTAL / TROWS, 512, 0, stream>>>(
      obs, ag, g, W1P, W2f, W3f, W4f, phi_b2, rho_b1, mean_b, logstd_b, out);
}

// Round 2
// 193.282 us; speedup vs baseline: 2.0083x; 2.0083x over previous
//
#include <hip/hip_runtime.h>
#include <hip/hip_bf16.h>

// ---------------------------------------------------------------------------
// SemanticActor fused forward, bf16 MFMA (gfx950) — Round 10
// R9 post-mortem: __launch_bounds__ 2nd arg is CUDA-style min BLOCKS/CU on
// this toolchain: (512,4) => 4 blk * 8 waves = 8 waves/SIMD => VGPR capped
// at 64 => massive scratch spills (FETCH 20MB->679MB, WRITE 20->539MB,
// MfmaUtil 11%). Occupancy DID hit 41% (2 blocks/CU) -> the single-buffer
// LDS change was right; only the register cap was wrong.
// R10: keep single-buffer HsBuf (LDS 50176B), restore (512,2) => VGPR<=128
// (R8 compiled to exactly 128 with this bound). 2 blocks/CU now fit on BOTH
// LDS and VGPR axes, no spills. Expect R8's structure at 2x occupancy.
// ---------------------------------------------------------------------------

#define B_TOTAL 65536
#define TROWS   64
#define RSTR    136   // rawS row stride elems: 272B = 17x16B -> optimal b128 phasing

typedef __attribute__((ext_vector_type(8))) short s8v;   // 8 x bf16
typedef __attribute__((ext_vector_type(4))) float f4v;   // MFMA C/D

__constant__ int c_PI[6] = {0,0,1,1,2,2};
__constant__ int c_PJ[6] = {1,2,0,2,0,1};
__constant__ int c_PF[6] = {0,0,1,0,1,1};
// inverse of FIRST_INDS / SECOND_INDS: raw ag/g col -> X col (or -1)
__constant__ int c_INV[2][30] = {
  {0,1,2,3,4,5,6,7,8,9,10,11,12,13,-1,14,15,16,-1,-1,17,18,-1,-1,-1,19,-1,-1,-1,-1},
  {0,1,2,3,4,5,6,7,8,9,-1,-1,-1,-1,10,-1,-1,-1,11,12,-1,-1,13,14,15,-1,16,17,18,19}};

static __device__ __forceinline__ short bf16s(float v) {
  __hip_bfloat16 h = __float2bfloat16(v);
  union { __hip_bfloat16 h; short s; } u; u.h = h; return u.s;
}

// ---- prep: one 512-elem fragment per wave; coalesced reads, b128 writes ----
// tasks: [0,384) W1P (p=wid>>6, nb=rem>>2, ks=rem&3) | [384,512) W2f |
//        [512,640) W3f | [640,648) W4f
__global__ __launch_bounds__(256)
void prep_weights(const float* __restrict__ phi_w1,
                  const float* __restrict__ phi_b1,
                  const float* __restrict__ phi_w2,
                  const float* __restrict__ rho_w1,
                  const float* __restrict__ mean_w,
                  const float* __restrict__ logstd_w,
                  __hip_bfloat16* __restrict__ W1P,
                  __hip_bfloat16* __restrict__ W2f,
                  __hip_bfloat16* __restrict__ W3f,
                  __hip_bfloat16* __restrict__ W4f) {
  const int wid  = (blockIdx.x * blockDim.x + threadIdx.x) >> 6;
  const int lane = threadIdx.x & 63;
  const int l15  = lane & 15;
  const int kq   = (lane >> 4) * 8;
  if (wid >= 648) return;
  union { short s[8]; s8v v; } o;
  __hip_bfloat16* dst;
  if (wid < 384) {
    const int p = wid >> 6, rem = wid & 63;
    const int nb = rem >> 2, ks = rem & 3;
    const int n = nb * 16 + l15;
    const int f = c_PF[p], oi = c_PI[p], oj = c_PJ[p];
#pragma unroll
    for (int j = 0; j < 8; ++j) {
      int k = ks * 32 + kq + j;
      float v = 0.0f;
      if (k < 30)       { int t = c_INV[f][k];      if (t >= 0) v = phi_w1[t * 256 + n]; }
      else if (k < 60)  { int t = c_INV[f][k - 30]; if (t >= 0) v = phi_w1[(30 + t) * 256 + n]; }
      else if (k < 70)  { v = phi_w1[(20 + k - 60) * 256 + n]; }
      else if (k < 115) { int q = (k - 70) / 15, t = (k - 70) - q * 15;
                          int c = (q == oi) ? 50 + t : (q == oj) ? 65 + t : -1;
                          if (c >= 0) v = phi_w1[c * 256 + n]; }
      else if (k == 115) v = phi_b1[n];   // bias via ones-column
      o.s[j] = bf16s(v);
    }
    dst = W1P + wid * 512 + lane * 8;
  } else if (wid < 512) {
    const int r = wid - 384;
    const int nb = r >> 3, ks = r & 7;
    const int n = nb * 16 + l15;
#pragma unroll
    for (int j = 0; j < 8; ++j)
      o.s[j] = bf16s(phi_w2[(ks * 32 + kq + j) * 256 + n]);
    dst = W2f + r * 512 + lane * 8;
  } else if (wid < 640) {
    const int r = wid - 512;
    const int nb = r >> 3, ks = r & 7;
    const int n = nb * 16 + l15;
#pragma unroll
    for (int j = 0; j < 8; ++j)
      o.s[j] = bf16s(rho_w1[(ks * 32 + kq + j) * 256 + n]);
    dst = W3f + r * 512 + lane * 8;
  } else {
    const int ks = wid - 640;
    const int n = l15;
#pragma unroll
    for (int j = 0; j < 8; ++j) {
      int k = ks * 32 + kq + j;
      float v = (n < 4) ? mean_w[k * 4 + n]
              : (n < 8) ? logstd_w[k * 4 + (n - 4)] : 0.0f;
      o.s[j] = bf16s(v);
    }
    dst = W4f + ks * 512 + lane * 8;
  }
  *reinterpret_cast<s8v*>(dst) = o.v;
}

static __device__ __forceinline__ unsigned pk2(float a, float b) {
  __hip_bfloat162 h = __float22bfloat162_rn(float2{a, b});
  union { __hip_bfloat162 h2; unsigned u; } cv; cv.h2 = h;
  return cv.u;
}

// ---- main: 512 threads (8 waves), 64 rows/block, wave = 32-col slice -------
// LDS 50176B -> 2 blocks/CU; launch_bounds(512,2)=min 2 BLOCKS/CU -> VGPR<=128
__global__ __launch_bounds__(512, 2)
void actor_main(const float* __restrict__ obs, const float* __restrict__ ag,
                const float* __restrict__ g,
                const __hip_bfloat16* __restrict__ W1P,
                const __hip_bfloat16* __restrict__ W2f,
                const __hip_bfloat16* __restrict__ W3f,
                const __hip_bfloat16* __restrict__ W4f,
                const float* __restrict__ b2, const float* __restrict__ b3,
                const float* __restrict__ meanb,
                const float* __restrict__ logstdb,
                float* __restrict__ out) {
  __shared__ __align__(16) __hip_bfloat16 rawS[TROWS * RSTR];   // 17408 B
  __shared__ __align__(16) __hip_bfloat16 HsBuf[4 * 8 * 512];   // 32768 B

  const int tid  = threadIdx.x;
  const int lane = tid & 63;
  const int w    = tid >> 6;      // wave 0..7 -> hidden cols [32w, 32w+32)
  const int l15  = lane & 15;
  const int quad = lane >> 4;
  const int r0   = blockIdx.x * TROWS;

  float4 b2v[2];
#pragma unroll
  for (int i = 0; i < 2; ++i)
    b2v[i] = *(const float4*)&b2[w * 32 + i * 16 + quad * 4];

  // persistent W2 fragments (once per block)
  s8v w2f[8][2];
#pragma unroll
  for (int i = 0; i < 2; ++i)
#pragma unroll
    for (int ks = 0; ks < 8; ++ks)
      w2f[ks][i] = *(const s8v*)&W2f[(((w * 2 + i) * 8 + ks) * 512) + lane * 8];

  // stage raw input [ag|g|obs|1|0] bf16 K=128 (vectorized: 2 b128 stores/thread)
  {
    const int row = tid >> 3;           // 0..63
    const int c0  = (tid & 7) * 16;     // 0..112
    const float* agr = ag  + (size_t)(r0 + row) * 30;
    const float* gr  = g   + (size_t)(r0 + row) * 30;
    const float* obr = obs + (size_t)(r0 + row) * 55;
    union { short s[16]; s8v v[2]; } o;
#pragma unroll
    for (int cc = 0; cc < 16; ++cc) {
      int c = c0 + cc;
      float v;
      if      (c < 30)  v = agr[c];
      else if (c < 60)  v = gr[c - 30];
      else if (c < 115) v = obr[c - 60];
      else if (c == 115) v = 1.0f;
      else              v = 0.0f;
      o.s[cc] = bf16s(v);
    }
    *reinterpret_cast<s8v*>(&rawS[row * RSTR + c0])     = o.v[0];
    *reinterpret_cast<s8v*>(&rawS[row * RSTR + c0 + 8]) = o.v[1];
  }

  // preload pair 0's W1P frags
  s8v w1c[4][2], w1n[4][2];
#pragma unroll
  for (int i = 0; i < 2; ++i)
#pragma unroll
    for (int ks = 0; ks < 4; ++ks)
      w1c[ks][i] = *(const s8v*)&W1P[(((w * 2 + i) * 4 + ks) * 512) + lane * 8];

  f4v agg[2][4];
#pragma unroll
  for (int i = 0; i < 2; ++i)
#pragma unroll
    for (int rt = 0; rt < 4; ++rt) agg[i][rt] = f4v{0.f, 0.f, 0.f, 0.f};

  const int ebase = l15 * 8 + (quad >> 1) * 128 + (quad & 1) * 4;

  __syncthreads();  // rawS staged

#pragma unroll 1
  for (int p = 0; p < 6; ++p) {
    __hip_bfloat16* buf = &HsBuf[0];

    // prefetch NEXT pair's W1P frags early (consumed only after GEMM2:
    // latency hidden under GEMM1 MFMAs + barriers + GEMM2 and, with 2
    // resident blocks, under the other block's compute)
    if (p < 5) {
      const __hip_bfloat16* nb = W1P + (p + 1) * 32768;
#pragma unroll
      for (int i = 0; i < 2; ++i)
#pragma unroll
        for (int ks = 0; ks < 4; ++ks)
          w1n[ks][i] = *(const s8v*)&nb[(((w * 2 + i) * 4 + ks) * 512) + lane * 8];
    }

    // GEMM1: h = W1P[p](A) x raw(B); K=128; raw B-frags from LDS
    f4v h[2][4];
#pragma unroll
    for (int i = 0; i < 2; ++i)
#pragma unroll
      for (int rt = 0; rt < 4; ++rt) h[i][rt] = f4v{0.f, 0.f, 0.f, 0.f};
#pragma unroll
    for (int ks = 0; ks < 4; ++ks) {
      s8v bx[4];
#pragma unroll
      for (int rt = 0; rt < 4; ++rt)
        bx[rt] = *(const s8v*)&rawS[(rt * 16 + l15) * RSTR + ks * 32 + quad * 8];
#pragma unroll
      for (int i = 0; i < 2; ++i)
#pragma unroll
        for (int rt = 0; rt < 4; ++rt)
          h[i][rt] = __builtin_amdgcn_mfma_f32_16x16x32_bf16(w1c[ks][i], bx[rt], h[i][rt], 0, 0, 0);
    }

    __syncthreads();  // pair p-1's GEMM2 reads of buf complete (single buffer)

    // epilogue: relu (bias folded via ones-column), pack -> b64 writes
#pragma unroll
    for (int i = 0; i < 2; ++i)
#pragma unroll
      for (int rt = 0; rt < 4; ++rt) {
        float v0 = fmaxf(h[i][rt][0], 0.f);
        float v1 = fmaxf(h[i][rt][1], 0.f);
        float v2 = fmaxf(h[i][rt][2], 0.f);
        float v3 = fmaxf(h[i][rt][3], 0.f);
        uint2 U; U.x = pk2(v0, v1); U.y = pk2(v2, v3);
        *reinterpret_cast<uint2*>(&buf[(rt * 8 + w) * 512 + i * 256 + ebase]) = U;
      }
    __syncthreads();  // H(p) visible

    // GEMM2: a2 = W2(A) x H(B); K=256; agg += relu(a2 + b2)
    f4v a2[2][4];
#pragma unroll
    for (int i = 0; i < 2; ++i)
#pragma unroll
      for (int rt = 0; rt < 4; ++rt) a2[i][rt] = f4v{0.f, 0.f, 0.f, 0.f};
#pragma unroll
    for (int ks = 0; ks < 8; ++ks) {
      s8v hf[4];
#pragma unroll
      for (int rt = 0; rt < 4; ++rt)
        hf[rt] = *(const s8v*)&buf[(rt * 8 + ks) * 512 + lane * 8];
#pragma unroll
      for (int i = 0; i < 2; ++i)
#pragma unroll
        for (int rt = 0; rt < 4; ++rt)
          a2[i][rt] = __builtin_amdgcn_mfma_f32_16x16x32_bf16(w2f[ks][i], hf[rt], a2[i][rt], 0, 0, 0);
    }
#pragma unroll
    for (int i = 0; i < 2; ++i)
#pragma unroll
      for (int rt = 0; rt < 4; ++rt) {
        agg[i][rt][0] += fmaxf(a2[i][rt][0] + b2v[i].x, 0.f);
        agg[i][rt][1] += fmaxf(a2[i][rt][1] + b2v[i].y, 0.f);
        agg[i][rt][2] += fmaxf(a2[i][rt][2] + b2v[i].z, 0.f);
        agg[i][rt][3] += fmaxf(a2[i][rt][3] + b2v[i].w, 0.f);
      }

    // rotate prefetch buffer
    if (p < 5) {
#pragma unroll
      for (int i = 0; i < 2; ++i)
#pragma unroll
        for (int ks = 0; ks < 4; ++ks)
          w1c[ks][i] = w1n[ks][i];
    }
  }

  // W3 frags + b3 (late-loaded)
  s8v w3f[8][2];
#pragma unroll
  for (int i = 0; i < 2; ++i)
#pragma unroll
    for (int ks = 0; ks < 8; ++ks)
      w3f[ks][i] = *(const s8v*)&W3f[(((w * 2 + i) * 8 + ks) * 512) + lane * 8];
  float4 b3v[2];
#pragma unroll
  for (int i = 0; i < 2; ++i)
    b3v[i] = *(const float4*)&b3[w * 32 + i * 16 + quad * 4];

  __syncthreads();  // last pair's GEMM2 reads done before stash overwrites buf

  // stash agg (bf16) into buf, frag-major
  {
    __hip_bfloat16* bufA = &HsBuf[0];
#pragma unroll
    for (int i = 0; i < 2; ++i)
#pragma unroll
      for (int rt = 0; rt < 4; ++rt) {
        uint2 U; U.x = pk2(agg[i][rt][0], agg[i][rt][1]);
        U.y = pk2(agg[i][rt][2], agg[i][rt][3]);
        *reinterpret_cast<uint2*>(&bufA[(rt * 8 + w) * 512 + i * 256 + ebase]) = U;
      }
  }
  __syncthreads();

  // GEMM3: hr = relu(W3(A) x agg(B) + b3); reads buf, then rewrites buf
  f4v a3[2][4];
#pragma unroll
  for (int i = 0; i < 2; ++i)
#pragma unroll
    for (int rt = 0; rt < 4; ++rt) a3[i][rt] = f4v{0.f, 0.f, 0.f, 0.f};
  {
    const __hip_bfloat16* bufA = &HsBuf[0];
#pragma unroll
    for (int ks = 0; ks < 8; ++ks) {
      s8v hf[4];
#pragma unroll
      for (int rt = 0; rt < 4; ++rt)
        hf[rt] = *(const s8v*)&bufA[(rt * 8 + ks) * 512 + lane * 8];
#pragma unroll
      for (int i = 0; i < 2; ++i)
#pragma unroll
        for (int rt = 0; rt < 4; ++rt)
          a3[i][rt] = __builtin_amdgcn_mfma_f32_16x16x32_bf16(w3f[ks][i], hf[rt], a3[i][rt], 0, 0, 0);
    }
  }
  __syncthreads();  // all GEMM3 reads of buf complete before rewrite
  {
    __hip_bfloat16* bufB = &HsBuf[0];
#pragma unroll
    for (int i = 0; i < 2; ++i)
#pragma unroll
      for (int rt = 0; rt < 4; ++rt) {
        float v0 = fmaxf(a3[i][rt][0] + b3v[i].x, 0.f);
        float v1 = fmaxf(a3[i][rt][1] + b3v[i].y, 0.f);
        float v2 = fmaxf(a3[i][rt][2] + b3v[i].z, 0.f);
        float v3 = fmaxf(a3[i][rt][3] + b3v[i].w, 0.f);
        uint2 U; U.x = pk2(v0, v1); U.y = pk2(v2, v3);
        *reinterpret_cast<uint2*>(&bufB[(rt * 8 + w) * 512 + i * 256 + ebase]) = U;
      }
  }
  __syncthreads();

  // GEMM4: heads; waves 0..3 take batch tile rt=w; reads buf
  if (w < 4) {
    const __hip_bfloat16* bufB = &HsBuf[0];
    f4v a4 = f4v{0.f, 0.f, 0.f, 0.f};
#pragma unroll
    for (int ks = 0; ks < 8; ++ks) {
      s8v w4 = *(const s8v*)&W4f[ks * 512 + lane * 8];
      s8v hf = *(const s8v*)&bufB[(w * 8 + ks) * 512 + lane * 8];
      a4 = __builtin_amdgcn_mfma_f32_16x16x32_bf16(w4, hf, a4, 0, 0, 0);
    }
    const int row = r0 + w * 16 + l15;
    if (quad == 0) {          // head cols 0..3 = mean
      float4 mb = *(const float4*)meanb;
      float4 o;
      o.x = a4[0] + mb.x; o.y = a4[1] + mb.y;
      o.z = a4[2] + mb.z; o.w = a4[3] + mb.w;
      *reinterpret_cast<float4*>(&out[(size_t)row * 4]) = o;
    } else if (quad == 1) {   // head cols 4..7 = logstd (clipped)
      float4 lb = *(const float4*)logstdb;
      float4 o;
      o.x = fminf(fmaxf(a4[0] + lb.x, -20.f), 2.f);
      o.y = fminf(fmaxf(a4[1] + lb.y, -20.f), 2.f);
      o.z = fminf(fmaxf(a4[2] + lb.z, -20.f), 2.f);
      o.w = fminf(fmaxf(a4[3] + lb.w, -20.f), 2.f);
      *reinterpret_cast<float4*>(&out[(size_t)B_TOTAL * 4 + (size_t)row * 4]) = o;
    }
  }
}

extern "C" void kernel_launch(void* const* d_in, const int* in_sizes, int n_in,
                              void* d_out, int out_size, void* d_ws, size_t ws_size,
                              hipStream_t stream) {
  const float* obs      = (const float*)d_in[0];
  const float* ag       = (const float*)d_in[1];
  const float* g        = (const float*)d_in[2];
  const float* phi_w1   = (const float*)d_in[3];
  const float* phi_b1   = (const float*)d_in[4];
  const float* phi_w2   = (const float*)d_in[5];
  const float* phi_b2   = (const float*)d_in[6];
  const float* rho_w1   = (const float*)d_in[7];
  const float* rho_b1   = (const float*)d_in[8];
  const float* mean_w   = (const float*)d_in[9];
  const float* mean_b   = (const float*)d_in[10];
  const float* logstd_w = (const float*)d_in[11];
  const float* logstd_b = (const float*)d_in[12];
  float* out = (float*)d_out;

  // ws (bf16): W1P 6x32768 | W2f 65536 | W3f 65536 | W4f 4096 elems
  char* ws = (char*)d_ws;
  __hip_bfloat16* W1P = (__hip_bfloat16*)(ws);
  __hip_bfloat16* W2f = (__hip_bfloat16*)(ws + 393216);
  __hip_bfloat16* W3f = (__hip_bfloat16*)(ws + 393216 + 131072);
  __hip_bfloat16* W4f = (__hip_bfloat16*)(ws + 393216 + 262144);

  prep_weights<<<162, 256, 0, stream>>>(phi_w1, phi_b1, phi_w2, rho_w1,
                                        mean_w, logstd_w, W1P, W2f, W3f, W4f);
  actor_main<<<B_TOTAL / TROWS, 512, 0, stream>>>(
      obs, ag, g, W1P, W2f, W3f, W4f, phi_b2, rho_b1, mean_b, logstd_b, out);
}